// Round 9
// baseline (237.641 us; speedup 1.0000x reference)
//
#include <hip/hip_runtime.h>
#include <cstdint>
#include <cstddef>

#define S 8192
#define Dm 1024
#define E 64
#define CAP 128
#define SEC 67108864ull   // S*E*CAP
// out layout (float32 elements):
//   [0] l_aux | [1,1+SEC) combine | [1+SEC,1+2SEC) dispatch | [1+2SEC,+64) counts
// out_size = 1 + 2*SEC + 64 = 134,217,793. Fill covers the first 134,217,792;
// the leftover element is exp_counts[63], written unconditionally by the scan.

#define GEMM_BLOCKS 256   // 32 tokens x 64 experts each (R5/R8 structure)
#define SCAN_BLOCKS 64    // 1 per expert, resident from t=0, spin-waits
#define FILL_BLOCKS 1728  // 256+64+1728 = 2048 = exactly the chip's block slots

typedef float f32x4 __attribute__((ext_vector_type(4)));

// ---------------- K1: everything fused ----------------
// GEMM blocks [0,256): R8 code verbatim; at end, release-add dcnt[0].
// Scan blocks [256,320): spin on dcnt[0]==256 (GEMM done), then do the
//   per-expert ballot scan + me-reduce ENTIRELY UNDER THE FILL (they only
//   read idx/gate/me_part); then spin on dcnt[1]==1728 (fill done) and flush
//   the 64KB of scatter/counts/l_aux writes (~1us exposed tail).
// Fill blocks [320,2048): grid-stride float4 zero of the 537MB output;
//   release-add dcnt[1] at end.
// Deadlock-free: all 2048 blocks co-resident; GEMM/fill wait on nobody.
__global__ __launch_bounds__(256) void k_main(const float* __restrict__ x,
                                              const float* __restrict__ w,
                                              float* __restrict__ gate,
                                              int* __restrict__ idx,
                                              float* __restrict__ me_part,
                                              unsigned* __restrict__ dcnt,
                                              float* __restrict__ out) {
    int bid = blockIdx.x;
    int tid = threadIdx.x;
    if (bid < GEMM_BLOCKS) {
        // ---- GEMM + softmax/argmax (R5/R8 champion structure) ----
        __shared__ float Al[32][66];   // row 264B: float2-aligned, 2-way max
        __shared__ float Wl[64][68];   // row 272B: float4-aligned, 2-way max
        __shared__ float sm[32];
        __shared__ float sinv[32];
        int tok = tid & 31;
        int eo = tid >> 5;
        int t0 = bid * 32;
        const float* asrc = x + (size_t)(t0 + (tid >> 3)) * Dm + (tid & 7) * 8;
        const float* wsrc0 = w + (size_t)(tid >> 3) * Dm + (tid & 7) * 8;
        const float* wsrc1 = wsrc0 + 32 * (size_t)Dm;
        float* adst = &Al[tid >> 3][(tid & 7) * 8];
        float* wdst0 = &Wl[tid >> 3][(tid & 7) * 8];
        float* wdst1 = &Wl[32 + (tid >> 3)][(tid & 7) * 8];

        float acc[8] = {0.f, 0.f, 0.f, 0.f, 0.f, 0.f, 0.f, 0.f};
        float4 pa0 = *(const float4*)(asrc + 0);
        float4 pa1 = *(const float4*)(asrc + 4);
        float4 pw0 = *(const float4*)(wsrc0 + 0);
        float4 pw1 = *(const float4*)(wsrc0 + 4);
        float4 pw2 = *(const float4*)(wsrc1 + 0);
        float4 pw3 = *(const float4*)(wsrc1 + 4);

        for (int ch = 0; ch < 16; ++ch) {
            __syncthreads();
            *(float2*)(adst + 0) = make_float2(pa0.x, pa0.y);
            *(float2*)(adst + 2) = make_float2(pa0.z, pa0.w);
            *(float2*)(adst + 4) = make_float2(pa1.x, pa1.y);
            *(float2*)(adst + 6) = make_float2(pa1.z, pa1.w);
            *(float4*)(wdst0 + 0) = pw0;
            *(float4*)(wdst0 + 4) = pw1;
            *(float4*)(wdst1 + 0) = pw2;
            *(float4*)(wdst1 + 4) = pw3;
            __syncthreads();
            if (ch < 15) {
                int kb = (ch + 1) * 64;
                pa0 = *(const float4*)(asrc + kb);
                pa1 = *(const float4*)(asrc + kb + 4);
                pw0 = *(const float4*)(wsrc0 + kb);
                pw1 = *(const float4*)(wsrc0 + kb + 4);
                pw2 = *(const float4*)(wsrc1 + kb);
                pw3 = *(const float4*)(wsrc1 + kb + 4);
            }
#pragma unroll 4
            for (int k4 = 0; k4 < 16; ++k4) {
                float2 aa = *(const float2*)&Al[tok][k4 * 4];
                float2 ab = *(const float2*)&Al[tok][k4 * 4 + 2];
#pragma unroll
                for (int j = 0; j < 8; ++j) {
                    float4 wv = *(const float4*)&Wl[eo * 8 + j][k4 * 4];
                    acc[j] = fmaf(ab.y, wv.w, fmaf(ab.x, wv.z,
                             fmaf(aa.y, wv.y, fmaf(aa.x, wv.x, acc[j]))));
                }
            }
        }
        __syncthreads();
#pragma unroll
        for (int j = 0; j < 8; ++j) Al[tok][eo * 8 + j] = acc[j];
        __syncthreads();
        if (tid < 32) {   // row phase: first-index argmax + exp-sum
            float m = Al[tid][0];
            int am = 0;
#pragma unroll
            for (int c = 1; c < E; ++c) {
                float v = Al[tid][c];
                if (v > m) { m = v; am = c; }
            }
            float ssum = 0.f;
#pragma unroll
            for (int c = 0; c < E; ++c) ssum += __expf(Al[tid][c] - m);
            float inv = 1.0f / ssum;
            gate[t0 + tid] = inv;
            idx[t0 + tid] = am;
            sm[tid] = m;
            sinv[tid] = inv;
        }
        __syncthreads();
        if (tid < E) {    // column phase: partial me sums (deterministic)
            float cs = 0.f;
#pragma unroll 8
            for (int r = 0; r < 32; ++r)
                cs += __expf(Al[r][tid] - sm[r]) * sinv[r];
            me_part[bid * E + tid] = cs;
        }
        __syncthreads();  // drains all global stores (vmcnt 0) before signal
        if (tid == 0)
            __hip_atomic_fetch_add(&dcnt[0], 1u, __ATOMIC_RELEASE,
                                   __HIP_MEMORY_SCOPE_AGENT);
    } else if (bid < GEMM_BLOCKS + SCAN_BLOCKS) {
        // ---- per-expert ordered scan + scatter (hidden under the fill) ----
        __shared__ int wsum[4];
        __shared__ float red[256];
        __shared__ int kt[CAP];
        int e = bid - GEMM_BLOCKS;
        int lane = tid & 63;
        int wid = tid >> 6;
        if (tid == 0) {   // wait: all GEMM blocks done (idx/gate/me_part ready)
            while (__hip_atomic_load(&dcnt[0], __ATOMIC_ACQUIRE,
                                     __HIP_MEMORY_SCOPE_AGENT) < GEMM_BLOCKS)
                __builtin_amdgcn_s_sleep(16);
        }
        __syncthreads();
        int running = 0;
        for (int ch = 0; ch < S / 256; ++ch) {
            int t = ch * 256 + tid;
            bool f = (idx[t] == e);
            unsigned long long b = __ballot(f);
            int pre = __popcll(b & ((1ull << lane) - 1ull));
            if (lane == 0) wsum[wid] = __popcll(b);
            __syncthreads();
            int off = running;
#pragma unroll
            for (int w2 = 0; w2 < 4; ++w2)
                if (w2 < wid) off += wsum[w2];
            int p = off + pre;
            if (f && p < CAP) kt[p] = t;   // slot p = arrival order
            running += wsum[0] + wsum[1] + wsum[2] + wsum[3];
            __syncthreads();
        }
        red[tid] = me_part[tid * E + e];   // me-reduce over 256 GEMM blocks
        __syncthreads();
        for (int s2 = 128; s2 > 0; s2 >>= 1) {
            if (tid < s2) red[tid] += red[tid + s2];
            __syncthreads();
        }
        // precompute the scatter into regs while the fill still runs
        int nk = running < CAP ? running : CAP;
        bool wr = tid < nk;
        size_t o = 0;
        float gv = 0.f;
        if (wr) {
            int t = kt[tid];
            o = 1 + (size_t)t * (E * CAP) + (size_t)e * CAP + (size_t)tid;
            gv = gate[t];
        }
        if (tid == 0) {   // wait: all fill blocks done (out is zeroed)
            while (__hip_atomic_load(&dcnt[1], __ATOMIC_ACQUIRE,
                                     __HIP_MEMORY_SCOPE_AGENT) < FILL_BLOCKS)
                __builtin_amdgcn_s_sleep(16);
        }
        __syncthreads();
        if (wr) {
            out[o] = gv;                   // combine_weights
            out[o + SEC] = 1.0f;           // dispatch_mask
        }
        if (tid == 0) {
            out[1 + 2 * SEC + e] = (float)running;   // exp_counts (pre-drop)
            float la = red[0] * (1.0f / (float)S) *
                       ((float)running / (float)S) * (float)E;
            atomicAdd(out, la);                      // l_aux
        }
    } else {
        // ---- 537MB zero-fill ----
        int fb = bid - (GEMM_BLOCKS + SCAN_BLOCKS);
        const unsigned N4 = (unsigned)((1ull + 2ull * SEC + 64ull) / 4ull);  // 33,554,448
        f32x4 z = {0.f, 0.f, 0.f, 0.f};
        f32x4* o4 = (f32x4*)out;
        for (unsigned i = (unsigned)fb * 256u + tid; i < N4; i += FILL_BLOCKS * 256u)
            o4[i] = z;
        __syncthreads();  // drain this block's stores before signaling
        if (tid == 0)
            __hip_atomic_fetch_add(&dcnt[1], 1u, __ATOMIC_RELEASE,
                                   __HIP_MEMORY_SCOPE_AGENT);
    }
}

extern "C" void kernel_launch(void* const* d_in, const int* in_sizes, int n_in,
                              void* d_out, int out_size, void* d_ws, size_t ws_size,
                              hipStream_t stream) {
    const float* x = (const float*)d_in[0];      // [S, Dm] fp32
    const float* w = (const float*)d_in[1];      // [E, Dm] fp32
    float* out = (float*)d_out;

    // ws layout
    float* me_part = (float*)d_ws;               // [256][64] floats = 64 KB
    float* gate = me_part + GEMM_BLOCKS * E;     // S floats
    int* idx = (int*)(gate + S);                 // S ints
    unsigned* dcnt = (unsigned*)(idx + S);       // 2 counters

    hipMemsetAsync(dcnt, 0, 2 * sizeof(unsigned), stream);
    k_main<<<dim3(GEMM_BLOCKS + SCAN_BLOCKS + FILL_BLOCKS), dim3(256), 0, stream>>>(
        x, w, gate, idx, me_part, dcnt, out);
}

// Round 10
// 160.673 us; speedup vs baseline: 1.4790x; 1.4790x over previous
//
#include <hip/hip_runtime.h>
#include <cstdint>
#include <cstddef>

#define S 8192
#define Dm 1024
#define E 64
#define CAP 128
#define SEC 67108864ull   // S*E*CAP
// out layout (float32 elements):
//   [0] l_aux | [1,1+SEC) combine | [1+SEC,1+2SEC) dispatch | [1+2SEC,+64) counts
// Coverage map (every element written every call):
//   K1 fill: chunks [SEC/4, 33554448) = elements [SEC, 134217792)  (zeros)
//   K2: counts[0..63], plus boundary elements SEC (combine t=8191,r=8191) and
//       2SEC (dispatch t=8191,r=8191) when targeted (else K1's zeros stand)
//   K3 merge: elements [1, SEC) with final combine values; element 0 = l_aux

#define GEMM_BLOCKS 256   // 32 tokens x 64 experts each (R8 champion structure)
#define FILL_BLOCKS 1792
#define N4ALL 33554448u   // chunks covering elements [0, 134217792)
#define NCMERGE 16777216u // SEC/4 chunks = elements [0, SEC)

typedef float f32x4 __attribute__((ext_vector_type(4)));

// ---------------- K1: {GEMM+softmax+argmax} + dispatch-half zero-fill --------
__global__ __launch_bounds__(256) void k_main(const float* __restrict__ x,
                                              const float* __restrict__ w,
                                              float* __restrict__ gate,
                                              int* __restrict__ idx,
                                              float* __restrict__ me_part,
                                              float* __restrict__ out) {
    int bid = blockIdx.x;
    int tid = threadIdx.x;
    if (bid < GEMM_BLOCKS) {
        __shared__ float Al[32][66];
        __shared__ float Wl[64][68];
        __shared__ float sm[32];
        __shared__ float sinv[32];
        int tok = tid & 31;
        int eo = tid >> 5;
        int t0 = bid * 32;
        const float* asrc = x + (size_t)(t0 + (tid >> 3)) * Dm + (tid & 7) * 8;
        const float* wsrc0 = w + (size_t)(tid >> 3) * Dm + (tid & 7) * 8;
        const float* wsrc1 = wsrc0 + 32 * (size_t)Dm;
        float* adst = &Al[tid >> 3][(tid & 7) * 8];
        float* wdst0 = &Wl[tid >> 3][(tid & 7) * 8];
        float* wdst1 = &Wl[32 + (tid >> 3)][(tid & 7) * 8];

        float acc[8] = {0.f, 0.f, 0.f, 0.f, 0.f, 0.f, 0.f, 0.f};
        float4 pa0 = *(const float4*)(asrc + 0);
        float4 pa1 = *(const float4*)(asrc + 4);
        float4 pw0 = *(const float4*)(wsrc0 + 0);
        float4 pw1 = *(const float4*)(wsrc0 + 4);
        float4 pw2 = *(const float4*)(wsrc1 + 0);
        float4 pw3 = *(const float4*)(wsrc1 + 4);

        for (int ch = 0; ch < 16; ++ch) {
            __syncthreads();
            *(float2*)(adst + 0) = make_float2(pa0.x, pa0.y);
            *(float2*)(adst + 2) = make_float2(pa0.z, pa0.w);
            *(float2*)(adst + 4) = make_float2(pa1.x, pa1.y);
            *(float2*)(adst + 6) = make_float2(pa1.z, pa1.w);
            *(float4*)(wdst0 + 0) = pw0;
            *(float4*)(wdst0 + 4) = pw1;
            *(float4*)(wdst1 + 0) = pw2;
            *(float4*)(wdst1 + 4) = pw3;
            __syncthreads();
            if (ch < 15) {
                int kb = (ch + 1) * 64;
                pa0 = *(const float4*)(asrc + kb);
                pa1 = *(const float4*)(asrc + kb + 4);
                pw0 = *(const float4*)(wsrc0 + kb);
                pw1 = *(const float4*)(wsrc0 + kb + 4);
                pw2 = *(const float4*)(wsrc1 + kb);
                pw3 = *(const float4*)(wsrc1 + kb + 4);
            }
#pragma unroll 4
            for (int k4 = 0; k4 < 16; ++k4) {
                float2 aa = *(const float2*)&Al[tok][k4 * 4];
                float2 ab = *(const float2*)&Al[tok][k4 * 4 + 2];
#pragma unroll
                for (int j = 0; j < 8; ++j) {
                    float4 wv = *(const float4*)&Wl[eo * 8 + j][k4 * 4];
                    acc[j] = fmaf(ab.y, wv.w, fmaf(ab.x, wv.z,
                             fmaf(aa.y, wv.y, fmaf(aa.x, wv.x, acc[j]))));
                }
            }
        }
        __syncthreads();
#pragma unroll
        for (int j = 0; j < 8; ++j) Al[tok][eo * 8 + j] = acc[j];
        __syncthreads();
        if (tid < 32) {   // first-index argmax + exp-sum
            float m = Al[tid][0];
            int am = 0;
#pragma unroll
            for (int c = 1; c < E; ++c) {
                float v = Al[tid][c];
                if (v > m) { m = v; am = c; }
            }
            float ssum = 0.f;
#pragma unroll
            for (int c = 0; c < E; ++c) ssum += __expf(Al[tid][c] - m);
            float inv = 1.0f / ssum;
            gate[t0 + tid] = inv;
            idx[t0 + tid] = am;
            sm[tid] = m;
            sinv[tid] = inv;
        }
        __syncthreads();
        if (tid < E) {    // partial me column sums (deterministic)
            float cs = 0.f;
#pragma unroll 8
            for (int r = 0; r < 32; ++r)
                cs += __expf(Al[r][tid] - sm[r]) * sinv[r];
            me_part[bid * E + tid] = cs;
        }
    } else {
        // zero-fill dispatch half + counts: chunks [SEC/4, N4ALL)
        int fb = bid - GEMM_BLOCKS;
        f32x4 z = {0.f, 0.f, 0.f, 0.f};
        f32x4* o4 = (f32x4*)out;
        for (unsigned i = (unsigned)(SEC / 4) + (unsigned)fb * 256u + tid;
             i < N4ALL; i += FILL_BLOCKS * 256u)
            o4[i] = z;
    }
}

// ---------------- K2: per-expert ordered scan (wave-synchronous) -------------
// 16 blocks x 256 = 64 waves; wave = expert. Deterministic ballot scan over
// tokens in order -> tg[t] = {tgt(int bitcast), gval}; counts; me reduce.
__global__ __launch_bounds__(256) void k_scan(const int* __restrict__ idx,
                                              const float* __restrict__ gate,
                                              const float* __restrict__ me_part,
                                              float2* __restrict__ tg,
                                              float* __restrict__ counts_ws,
                                              float* __restrict__ me_ws,
                                              float* __restrict__ out) {
    int lane = threadIdx.x & 63;
    int e = (blockIdx.x << 2) | (threadIdx.x >> 6);   // 0..63
    int running = 0;
    int cur = idx[lane];
    for (int ch = 0; ch < S / 64; ++ch) {
        int t = ch * 64 + lane;
        int nxt = (ch < S / 64 - 1) ? idx[(ch + 1) * 64 + lane] : 0;
        bool f = (cur == e);
        unsigned long long b = __ballot(f);
        if (f) {
            int p = running + __popcll(b & ((1ull << lane) - 1ull));
            int tgt = (p < CAP) ? e * CAP + p : -1;
            tg[t] = make_float2(__int_as_float(tgt), gate[t]);
            if (t == S - 1 && tgt == S - 1) {   // boundary (t=8191,r=8191)
                out[SEC] = gate[t];             // last combine element
                out[2 * SEC] = 1.0f;            // last dispatch element
            }
        }
        running += __popcll(b);
        cur = nxt;
    }
    if (lane == 0) {
        out[1 + 2 * SEC + e] = (float)running;  // exp_counts (pre-drop)
        counts_ws[e] = (float)running;
    }
    // me reduction over 256 GEMM blocks
    float ms = 0.f;
#pragma unroll
    for (int k = 0; k < 4; ++k)
        ms += me_part[(lane + k * 64) * E + e];
#pragma unroll
    for (int off = 32; off > 0; off >>= 1)
        ms += __shfl_down(ms, off, 64);
    if (lane == 0) me_ws[e] = ms;
}

// ---------------- K3: merge-fill of the combine half + l_aux -----------------
// Blocks [0,2048): write elements [1, SEC) directly with final combine values
//   (write-bound; ~50 VALU per 16B chunk hides under the store budget).
// Block 2048: l_aux from counts_ws/me_ws -> out[0].
__global__ __launch_bounds__(256) void k_merge(const float2* __restrict__ tg,
                                               const float* __restrict__ counts_ws,
                                               const float* __restrict__ me_ws,
                                               float* __restrict__ out) {
    int bid = blockIdx.x;
    int tid = threadIdx.x;
    if (bid == 2048) {
        if (tid < E) {
            float la = me_ws[tid] * (1.0f / (float)S) *
                       (counts_ws[tid] / (float)S) * (float)E;
#pragma unroll
            for (int off = 32; off > 0; off >>= 1)
                la += __shfl_down(la, off, 64);
            if (tid == 0) out[0] = la;
        }
        return;
    }
    f32x4* o4 = (f32x4*)out;
    for (unsigned i = (unsigned)bid * 256u + tid; i < NCMERGE; i += 2048u * 256u) {
        unsigned e0 = 4u * i;
        f32x4 v = {0.f, 0.f, 0.f, 0.f};
#pragma unroll
        for (int j = 0; j < 4; ++j) {
            int c = (int)e0 + j - 1;            // combine index
            if (c >= 0) {
                int t = c >> 13;
                int r = c & 8191;
                float2 g = tg[t];               // L1-broadcast (t uniform-ish)
                if (r == __float_as_int(g.x)) v[j] = g.y;
            }
        }
        if (i == 0) {            // skip element 0 (l_aux): scalar stores 1..3
            out[1] = v.y; out[2] = v.z; out[3] = v.w;
        } else {
            o4[i] = v;
        }
    }
}

extern "C" void kernel_launch(void* const* d_in, const int* in_sizes, int n_in,
                              void* d_out, int out_size, void* d_ws, size_t ws_size,
                              hipStream_t stream) {
    const float* x = (const float*)d_in[0];      // [S, Dm] fp32
    const float* w = (const float*)d_in[1];      // [E, Dm] fp32
    float* out = (float*)d_out;

    // ws layout
    float* me_part = (float*)d_ws;               // [256][64] = 64 KB
    float* gate = me_part + GEMM_BLOCKS * E;     // S floats
    int* idx = (int*)(gate + S);                 // S ints
    float2* tg = (float2*)(idx + S);             // S float2 = 64 KB
    float* counts_ws = (float*)(tg + S);         // 64 floats
    float* me_ws = counts_ws + E;                // 64 floats

    k_main<<<dim3(GEMM_BLOCKS + FILL_BLOCKS), dim3(256), 0, stream>>>(
        x, w, gate, idx, me_part, out);
    k_scan<<<dim3(16), dim3(256), 0, stream>>>(
        idx, gate, me_part, tg, counts_ws, me_ws, out);
    k_merge<<<dim3(2049), dim3(256), 0, stream>>>(tg, counts_ws, me_ws, out);
}